// Round 1
// baseline (1655.283 us; speedup 1.0000x reference)
//
#include <hip/hip_runtime.h>

#define NFEAT 128
#define NHID  256
#define BM    32
#define ATS   36   // At LDS stride (floats): %4==0 for float4 align, breaks 32-bank pattern

// ---------------- degree / norm ----------------
__global__ void k_deg(const int* __restrict__ dst, int E, float* __restrict__ degf) {
  int i = blockIdx.x * blockDim.x + threadIdx.x;
  if (i < E) unsafeAtomicAdd(&degf[dst[i]], 1.0f);
}

__global__ void k_inv(float* __restrict__ buf, int N) {
  int i = blockIdx.x * blockDim.x + threadIdx.x;
  if (i < N) {
    float d = buf[i] + 1.0f;            // +1 self loop
    buf[i] = rsqrtf(fmaxf(d, 1.0f));
  }
}

// ---------------- layer-1 aggregation of X (128 feats) ----------------
// virtual edges [0,E) = real, [E,E+N) = self loops. 32 threads/edge, float4 each.
__global__ void k_agg1(const float4* __restrict__ x4, const int* __restrict__ src,
                       const int* __restrict__ dst, const float* __restrict__ inv,
                       float* __restrict__ agg, int E, int N) {
  int gid = blockIdx.x * blockDim.x + threadIdx.x;
  int e = gid >> 5, f = gid & 31;
  if (e >= E + N) return;
  int s, d;
  if (e < E) { s = src[e]; d = dst[e]; } else { s = d = e - E; }
  float c = inv[s] * inv[d];
  float4 v = x4[s * 32 + f];
  float* ap = agg + ((size_t)d * NFEAT + f * 4);
  unsafeAtomicAdd(ap + 0, v.x * c);
  unsafeAtomicAdd(ap + 1, v.y * c);
  unsafeAtomicAdd(ap + 2, v.z * c);
  unsafeAtomicAdd(ap + 3, v.w * c);
}

// ---------------- fused GEMM: z = relu(agg @ W1 + b1) @ W2 ----------------
// block = 256 threads, tile BM=32 rows x 256 cols, K=128.
// wave (64 lanes) owns 8 rows; lane owns 4 cols. acc[8] float4.
__global__ __launch_bounds__(256, 2) void k_gemm_fused(
    const float* __restrict__ agg, const float* __restrict__ W1,
    const float* __restrict__ b1, const float* __restrict__ W2,
    float* __restrict__ z, int N) {
  __shared__ float At[NFEAT * ATS];   // A transposed: At[k*ATS + r], 18432 B
  __shared__ float Wt[32 * NHID];     // one K-chunk of W1, 32768 B
  int t = threadIdx.x;
  int m0 = blockIdx.x * BM;

  // load A tile (32 rows x 128 k), store transposed
  {
    int r = t >> 3;              // 0..31
    int kq = (t & 7) * 4;        // k quad base
    const float4* a4 = (const float4*)(agg + (size_t)(m0 + r) * NFEAT);
    bool ok = (m0 + r) < N;
#pragma unroll
    for (int p = 0; p < 4; ++p) {
      int k0 = kq + p * 32;
      float4 v = ok ? a4[k0 >> 2] : make_float4(0.f, 0.f, 0.f, 0.f);
      At[(k0 + 0) * ATS + r] = v.x;
      At[(k0 + 1) * ATS + r] = v.y;
      At[(k0 + 2) * ATS + r] = v.z;
      At[(k0 + 3) * ATS + r] = v.w;
    }
  }

  int rg = t >> 6;      // wave id -> row group
  int cg = t & 63;      // lane -> col group
  int r0 = rg * 8;
  int rq = r0 >> 2;     // float4 offset of r0 within an At row

  float4 acc[8];
#pragma unroll
  for (int i = 0; i < 8; ++i) acc[i] = make_float4(0.f, 0.f, 0.f, 0.f);

  const float4* At4 = (const float4*)At;
  const float4* Wt4 = (const float4*)Wt;
  const float4* W14 = (const float4*)W1;

  for (int kc = 0; kc < 4; ++kc) {
    __syncthreads();   // At ready (kc=0) / Wt readers done (kc>0)
#pragma unroll
    for (int i = 0; i < 8; ++i) {
      int idx = t + i * 256;                  // float4 index within 32x256 chunk
      ((float4*)Wt)[idx] = W14[kc * 2048 + idx];
    }
    __syncthreads();
#pragma unroll 8
    for (int kk = 0; kk < 32; ++kk) {
      int k = kc * 32 + kk;
      float4 w  = Wt4[kk * 64 + cg];          // stride-1 across lanes
      float4 a0 = At4[9 * k + rq];            // broadcast (same addr all lanes)
      float4 a1 = At4[9 * k + rq + 1];
      float av[8] = {a0.x, a0.y, a0.z, a0.w, a1.x, a1.y, a1.z, a1.w};
#pragma unroll
      for (int rr = 0; rr < 8; ++rr) {
        acc[rr].x = fmaf(av[rr], w.x, acc[rr].x);
        acc[rr].y = fmaf(av[rr], w.y, acc[rr].y);
        acc[rr].z = fmaf(av[rr], w.z, acc[rr].z);
        acc[rr].w = fmaf(av[rr], w.w, acc[rr].w);
      }
    }
  }

  // epilogue: +b1, relu, dot with W2 -> per-row partial; wave64 reduce
  int c0 = cg * 4;
  float4 bb = *(const float4*)(b1 + c0);
  float4 w2 = *(const float4*)(W2 + c0);
#pragma unroll
  for (int rr = 0; rr < 8; ++rr) {
    float hx = fmaxf(acc[rr].x + bb.x, 0.f);
    float hy = fmaxf(acc[rr].y + bb.y, 0.f);
    float hz = fmaxf(acc[rr].z + bb.z, 0.f);
    float hw = fmaxf(acc[rr].w + bb.w, 0.f);
    float p = hx * w2.x + hy * w2.y + hz * w2.z + hw * w2.w;
#pragma unroll
    for (int off = 32; off > 0; off >>= 1) p += __shfl_xor(p, off);
    if (cg == 0) {
      int row = m0 + r0 + rr;
      if (row < N) z[row] = p;
    }
  }
}

// ---------------- layer-2 aggregation (scalar) ----------------
__global__ void k_edge2(const int* __restrict__ src, const int* __restrict__ dst,
                        const float* __restrict__ inv, const float* __restrict__ z,
                        float* __restrict__ out, int E) {
  int e = blockIdx.x * blockDim.x + threadIdx.x;
  if (e < E) {
    int s = src[e], d = dst[e];
    unsafeAtomicAdd(&out[d], inv[s] * inv[d] * z[s]);
  }
}

__global__ void k_final(const float* __restrict__ inv, const float* __restrict__ z,
                        const float* __restrict__ b2, float* __restrict__ out, int N) {
  int i = blockIdx.x * blockDim.x + threadIdx.x;
  if (i < N) out[i] += inv[i] * inv[i] * z[i] + b2[0];
}

extern "C" void kernel_launch(void* const* d_in, const int* in_sizes, int n_in,
                              void* d_out, int out_size, void* d_ws, size_t ws_size,
                              hipStream_t stream) {
  const float* x  = (const float*)d_in[0];
  const int*   ei = (const int*)d_in[1];
  const float* W1 = (const float*)d_in[2];
  const float* b1 = (const float*)d_in[3];
  const float* W2 = (const float*)d_in[4];
  const float* b2 = (const float*)d_in[5];
  int N = in_sizes[0] / NFEAT;       // 50000
  int E = in_sizes[1] / 2;           // 800000
  const int* src = ei;
  const int* dst = ei + E;
  float* out = (float*)d_out;

  // workspace layout (all 256B-aligned via 64-float padding)
  int Npad = (N + 63) & ~63;
  float* inv = (float*)d_ws;         // N (degree, then 1/sqrt(deg) in place)
  float* z   = inv + Npad;           // N
  float* agg = z + Npad;             // N*128

  hipMemsetAsync(inv, 0, (size_t)N * sizeof(float), stream);
  hipMemsetAsync(agg, 0, (size_t)N * NFEAT * sizeof(float), stream);
  hipMemsetAsync(out, 0, (size_t)out_size * sizeof(float), stream);

  k_deg<<<(E + 255) / 256, 256, 0, stream>>>(dst, E, inv);
  k_inv<<<(N + 255) / 256, 256, 0, stream>>>(inv, N);

  long long tot = (long long)(E + N) * 32;
  k_agg1<<<(int)((tot + 255) / 256), 256, 0, stream>>>(
      (const float4*)x, src, dst, inv, agg, E, N);

  k_gemm_fused<<<(N + BM - 1) / BM, 256, 0, stream>>>(agg, W1, b1, W2, z, N);

  k_edge2<<<(E + 255) / 256, 256, 0, stream>>>(src, dst, inv, z, out, E);
  k_final<<<(N + 255) / 256, 256, 0, stream>>>(inv, z, b2, out, N);
}

// Round 2
// 349.771 us; speedup vs baseline: 4.7325x; 4.7325x over previous
//
#include <hip/hip_runtime.h>

#define NFEAT 128
#define NHID  256
#define BM    32
#define ATS   36   // At LDS stride (floats): %4==0 for float4 align, breaks 32-bank pattern

// ---------------- degree histogram (int atomics) ----------------
__global__ void k_hist(const int* __restrict__ dst, int E, int* __restrict__ deg) {
  int i = blockIdx.x * blockDim.x + threadIdx.x;
  if (i < E) atomicAdd(&deg[dst[i]], 1);
}

// ---------------- single-block scan: row_ptr (exclusive) + inv ----------------
// 1024 threads; wave-shuffle inclusive scan, LDS scan of 16 wave sums.
__global__ __launch_bounds__(1024) void k_scan(const int* __restrict__ deg, int N,
                                               int* __restrict__ row_ptr,
                                               float* __restrict__ inv) {
  __shared__ int wsum[16];
  __shared__ int s_running;
  int tid = threadIdx.x, lane = tid & 63, wid = tid >> 6;
  if (tid == 0) s_running = 0;
  __syncthreads();
  int ntiles = (N + 1023) / 1024;
  for (int tile = 0; tile < ntiles; ++tile) {
    int idx = tile * 1024 + tid;
    int v = (idx < N) ? deg[idx] : 0;
    int s = v;
#pragma unroll
    for (int off = 1; off < 64; off <<= 1) {
      int t = __shfl_up(s, off);
      if (lane >= off) s += t;
    }
    if (lane == 63) wsum[wid] = s;
    __syncthreads();                       // wsum ready
    int wbase = 0, total = 0;
#pragma unroll
    for (int w = 0; w < 16; ++w) {
      int t = wsum[w];
      total += t;
      if (w < wid) wbase += t;
    }
    int base = s_running;
    if (idx < N) {
      row_ptr[idx] = base + (wbase + s - v);       // exclusive
      inv[idx] = rsqrtf((float)(v + 1));           // +1 self loop
    }
    __syncthreads();                       // all reads of s_running/wsum done
    if (tid == 0) s_running = base + total;
  }
  __syncthreads();
  if (tid == 0) row_ptr[N] = s_running;
}

// ---------------- scatter edges into CSR order ----------------
__global__ void k_scatter(const int* __restrict__ src, const int* __restrict__ dst,
                          const int* __restrict__ row_ptr, int* __restrict__ cursor,
                          int* __restrict__ col, int E) {
  int e = blockIdx.x * blockDim.x + threadIdx.x;
  if (e < E) {
    int d = dst[e];
    int pos = row_ptr[d] + atomicAdd(&cursor[d], 1);
    col[pos] = src[e];
  }
}

// ---------------- layer-1 aggregation: one wave per node, no atomics ----------------
__global__ void k_agg1_csr(const float2* __restrict__ x2, const int* __restrict__ col,
                           const int* __restrict__ row_ptr, const float* __restrict__ inv,
                           float2* __restrict__ agg, int N) {
  int gid = blockIdx.x * blockDim.x + threadIdx.x;
  int node = gid >> 6, lane = gid & 63;
  if (node >= N) return;
  int beg = row_ptr[node], end = row_ptr[node + 1];
  float invd = inv[node];
  // self loop
  float2 xd = x2[(size_t)node * 64 + lane];
  float cs = invd * invd;
  float2 acc = make_float2(xd.x * cs, xd.y * cs);
  int p = beg;
  for (; p + 1 < end; p += 2) {           // 2-way ILP on the gather chain
    int s0 = col[p], s1 = col[p + 1];
    float c0 = inv[s0] * invd, c1 = inv[s1] * invd;
    float2 v0 = x2[(size_t)s0 * 64 + lane];
    float2 v1 = x2[(size_t)s1 * 64 + lane];
    acc.x = fmaf(v0.x, c0, acc.x); acc.y = fmaf(v0.y, c0, acc.y);
    acc.x = fmaf(v1.x, c1, acc.x); acc.y = fmaf(v1.y, c1, acc.y);
  }
  if (p < end) {
    int s0 = col[p];
    float c0 = inv[s0] * invd;
    float2 v0 = x2[(size_t)s0 * 64 + lane];
    acc.x = fmaf(v0.x, c0, acc.x); acc.y = fmaf(v0.y, c0, acc.y);
  }
  agg[(size_t)node * 64 + lane] = acc;
}

// ---------------- fused GEMM: cz = inv * (relu(agg @ W1 + b1) @ W2) ----------------
__global__ __launch_bounds__(256, 2) void k_gemm_fused(
    const float* __restrict__ agg, const float* __restrict__ W1,
    const float* __restrict__ b1, const float* __restrict__ W2,
    const float* __restrict__ inv, float* __restrict__ cz, int N) {
  __shared__ float At[NFEAT * ATS];
  __shared__ float Wt[32 * NHID];
  int t = threadIdx.x;
  int m0 = blockIdx.x * BM;

  {
    int r = t >> 3;
    int kq = (t & 7) * 4;
    const float4* a4 = (const float4*)(agg + (size_t)(m0 + r) * NFEAT);
    bool ok = (m0 + r) < N;
#pragma unroll
    for (int p = 0; p < 4; ++p) {
      int k0 = kq + p * 32;
      float4 v = ok ? a4[k0 >> 2] : make_float4(0.f, 0.f, 0.f, 0.f);
      At[(k0 + 0) * ATS + r] = v.x;
      At[(k0 + 1) * ATS + r] = v.y;
      At[(k0 + 2) * ATS + r] = v.z;
      At[(k0 + 3) * ATS + r] = v.w;
    }
  }

  int rg = t >> 6, cg = t & 63;
  int r0 = rg * 8, rq = r0 >> 2;

  float4 acc[8];
#pragma unroll
  for (int i = 0; i < 8; ++i) acc[i] = make_float4(0.f, 0.f, 0.f, 0.f);

  const float4* At4 = (const float4*)At;
  const float4* Wt4 = (const float4*)Wt;
  const float4* W14 = (const float4*)W1;

  for (int kc = 0; kc < 4; ++kc) {
    __syncthreads();
#pragma unroll
    for (int i = 0; i < 8; ++i) {
      int idx = t + i * 256;
      ((float4*)Wt)[idx] = W14[kc * 2048 + idx];
    }
    __syncthreads();
#pragma unroll 8
    for (int kk = 0; kk < 32; ++kk) {
      int k = kc * 32 + kk;
      float4 w  = Wt4[kk * 64 + cg];
      float4 a0 = At4[9 * k + rq];
      float4 a1 = At4[9 * k + rq + 1];
      float av[8] = {a0.x, a0.y, a0.z, a0.w, a1.x, a1.y, a1.z, a1.w};
#pragma unroll
      for (int rr = 0; rr < 8; ++rr) {
        acc[rr].x = fmaf(av[rr], w.x, acc[rr].x);
        acc[rr].y = fmaf(av[rr], w.y, acc[rr].y);
        acc[rr].z = fmaf(av[rr], w.z, acc[rr].z);
        acc[rr].w = fmaf(av[rr], w.w, acc[rr].w);
      }
    }
  }

  int c0 = cg * 4;
  float4 bb = *(const float4*)(b1 + c0);
  float4 w2 = *(const float4*)(W2 + c0);
#pragma unroll
  for (int rr = 0; rr < 8; ++rr) {
    float hx = fmaxf(acc[rr].x + bb.x, 0.f);
    float hy = fmaxf(acc[rr].y + bb.y, 0.f);
    float hz = fmaxf(acc[rr].z + bb.z, 0.f);
    float hw = fmaxf(acc[rr].w + bb.w, 0.f);
    float pp = hx * w2.x + hy * w2.y + hz * w2.z + hw * w2.w;
#pragma unroll
    for (int off = 32; off > 0; off >>= 1) pp += __shfl_xor(pp, off);
    if (cg == 0) {
      int row = m0 + r0 + rr;
      if (row < N) cz[row] = inv[row] * pp;
    }
  }
}

// ---------------- layer-2 aggregation: thread per node ----------------
__global__ void k_agg2(const int* __restrict__ col, const int* __restrict__ row_ptr,
                       const float* __restrict__ inv, const float* __restrict__ cz,
                       const float* __restrict__ b2, float* __restrict__ out, int N) {
  int i = blockIdx.x * blockDim.x + threadIdx.x;
  if (i >= N) return;
  int beg = row_ptr[i], end = row_ptr[i + 1];
  float acc = cz[i];                       // self loop: inv^2*z = inv*cz ... folded below
  for (int p = beg; p < end; ++p) acc += cz[col[p]];
  out[i] = inv[i] * acc + b2[0];
}

extern "C" void kernel_launch(void* const* d_in, const int* in_sizes, int n_in,
                              void* d_out, int out_size, void* d_ws, size_t ws_size,
                              hipStream_t stream) {
  const float* x  = (const float*)d_in[0];
  const int*   ei = (const int*)d_in[1];
  const float* W1 = (const float*)d_in[2];
  const float* b1 = (const float*)d_in[3];
  const float* W2 = (const float*)d_in[4];
  const float* b2 = (const float*)d_in[5];
  int N = in_sizes[0] / NFEAT;
  int E = in_sizes[1] / 2;
  const int* src = ei;
  const int* dst = ei + E;
  float* out = (float*)d_out;

  // workspace carve-up (256B-aligned chunks)
  char* w = (char*)d_ws;
  size_t o = 0;
  auto carve = [&](size_t bytes) { char* p = w + o; o += (bytes + 255) & ~(size_t)255; return p; };
  int*   deg     = (int*)  carve((size_t)N * 4);        // dead after k_scan
  int*   row_ptr = (int*)  carve((size_t)(N + 1) * 4);
  int*   cursor  = (int*)  carve((size_t)N * 4);
  float* inv     = (float*)carve((size_t)N * 4);
  int*   col     = (int*)  carve((size_t)E * 4);
  float* agg     = (float*)carve((size_t)N * NFEAT * 4);
  float* cz      = (float*)deg;                          // overlay: deg dead by GEMM time

  hipMemsetAsync(deg, 0, (size_t)N * sizeof(int), stream);
  hipMemsetAsync(cursor, 0, (size_t)N * sizeof(int), stream);

  k_hist<<<(E + 255) / 256, 256, 0, stream>>>(dst, E, deg);
  k_scan<<<1, 1024, 0, stream>>>(deg, N, row_ptr, inv);
  k_scatter<<<(E + 255) / 256, 256, 0, stream>>>(src, dst, row_ptr, cursor, col, E);

  long long tot = (long long)N * 64;
  k_agg1_csr<<<(int)((tot + 255) / 256), 256, 0, stream>>>(
      (const float2*)x, col, row_ptr, inv, (float2*)agg, N);

  k_gemm_fused<<<(N + BM - 1) / BM, 256, 0, stream>>>(agg, W1, b1, W2, inv, cz, N);

  k_agg2<<<(N + 255) / 256, 256, 0, stream>>>(col, row_ptr, inv, cz, b2, out, N);
}

// Round 3
// 310.503 us; speedup vs baseline: 5.3310x; 1.1265x over previous
//
#include <hip/hip_runtime.h>

#define NFEAT 128
#define NHID  256
#define BM    32
#define ATS   36   // At LDS stride (floats): %4==0 for float4 align, breaks 32-bank pattern

// ---------------- degree histogram (int atomics) ----------------
__global__ void k_hist(const int* __restrict__ dst, int E, int* __restrict__ deg) {
  int i = blockIdx.x * blockDim.x + threadIdx.x;
  if (i < E) atomicAdd(&deg[dst[i]], 1);
}

// ---------------- 3-phase parallel scan ----------------
// phase 1: each 1024-block scans its tile, writes local-exclusive + block total
__global__ __launch_bounds__(1024) void k_scan1(const int* __restrict__ deg, int N,
                                                int* __restrict__ row_ptr,
                                                float* __restrict__ inv,
                                                int* __restrict__ partials) {
  __shared__ int wsum[16];
  int tid = threadIdx.x, lane = tid & 63, wid = tid >> 6;
  int idx = blockIdx.x * 1024 + tid;
  int v = (idx < N) ? deg[idx] : 0;
  int s = v;
#pragma unroll
  for (int off = 1; off < 64; off <<= 1) {
    int t = __shfl_up(s, off);
    if (lane >= off) s += t;
  }
  if (lane == 63) wsum[wid] = s;
  __syncthreads();
  int wbase = 0, total = 0;
#pragma unroll
  for (int w = 0; w < 16; ++w) {
    int t = wsum[w];
    total += t;
    if (w < wid) wbase += t;
  }
  if (idx < N) {
    row_ptr[idx] = wbase + (s - v);            // block-local exclusive
    inv[idx] = rsqrtf((float)(v + 1));         // +1 self loop
  }
  if (tid == 0) partials[blockIdx.x] = total;
}

// phase 2: single wave scans block totals in-place -> exclusive bases
__global__ __launch_bounds__(64) void k_scan2(int* __restrict__ partials, int nparts,
                                              int* __restrict__ row_ptr_N) {
  int lane = threadIdx.x;
  int running = 0;
  for (int base = 0; base < nparts; base += 64) {
    int idx = base + lane;
    int v = (idx < nparts) ? partials[idx] : 0;
    int s = v;
#pragma unroll
    for (int off = 1; off < 64; off <<= 1) {
      int t = __shfl_up(s, off);
      if (lane >= off) s += t;
    }
    if (idx < nparts) partials[idx] = running + (s - v);
    running += __shfl(s, 63);
  }
  if (lane == 0) *row_ptr_N = running;
}

// phase 3: apply block bases; also init cursor = final row_ptr
__global__ void k_scan3(int* __restrict__ row_ptr, const int* __restrict__ partials,
                        int* __restrict__ cursor, int N) {
  int idx = blockIdx.x * blockDim.x + threadIdx.x;
  if (idx < N) {
    int v = row_ptr[idx] + partials[idx >> 10];
    row_ptr[idx] = v;
    cursor[idx] = v;
  }
}

// ---------------- scatter edges into CSR order ----------------
__global__ void k_scatter(const int* __restrict__ src, const int* __restrict__ dst,
                          int* __restrict__ cursor, int* __restrict__ col, int E) {
  int e = blockIdx.x * blockDim.x + threadIdx.x;
  if (e < E) {
    int pos = atomicAdd(&cursor[dst[e]], 1);
    col[pos] = src[e];
  }
}

// ---------------- layer-1 aggregation: one wave per node, no atomics ----------------
__global__ void k_agg1_csr(const float2* __restrict__ x2, const int* __restrict__ col,
                           const int* __restrict__ row_ptr, const float* __restrict__ inv,
                           float2* __restrict__ agg, int N) {
  int gid = blockIdx.x * blockDim.x + threadIdx.x;
  int node = gid >> 6, lane = gid & 63;
  if (node >= N) return;
  int beg = row_ptr[node], end = row_ptr[node + 1];
  float invd = inv[node];
  float2 xd = x2[(size_t)node * 64 + lane];
  float cs = invd * invd;
  float2 acc = make_float2(xd.x * cs, xd.y * cs);
  int p = beg;
  for (; p + 3 < end; p += 4) {            // 4-way ILP on the gather chain
    int s0 = col[p], s1 = col[p + 1], s2 = col[p + 2], s3 = col[p + 3];
    float c0 = inv[s0] * invd, c1 = inv[s1] * invd;
    float c2 = inv[s2] * invd, c3 = inv[s3] * invd;
    float2 v0 = x2[(size_t)s0 * 64 + lane];
    float2 v1 = x2[(size_t)s1 * 64 + lane];
    float2 v2 = x2[(size_t)s2 * 64 + lane];
    float2 v3 = x2[(size_t)s3 * 64 + lane];
    acc.x = fmaf(v0.x, c0, acc.x); acc.y = fmaf(v0.y, c0, acc.y);
    acc.x = fmaf(v1.x, c1, acc.x); acc.y = fmaf(v1.y, c1, acc.y);
    acc.x = fmaf(v2.x, c2, acc.x); acc.y = fmaf(v2.y, c2, acc.y);
    acc.x = fmaf(v3.x, c3, acc.x); acc.y = fmaf(v3.y, c3, acc.y);
  }
  for (; p < end; ++p) {
    int s0 = col[p];
    float c0 = inv[s0] * invd;
    float2 v0 = x2[(size_t)s0 * 64 + lane];
    acc.x = fmaf(v0.x, c0, acc.x); acc.y = fmaf(v0.y, c0, acc.y);
  }
  agg[(size_t)node * 64 + lane] = acc;
}

// ---------------- fused GEMM: cz = inv * (relu(agg @ W1 + b1) @ W2) ----------------
// Wt double-buffered through registers: load chunk kc+1 while computing kc.
__global__ __launch_bounds__(256, 3) void k_gemm_fused(
    const float* __restrict__ agg, const float* __restrict__ W1,
    const float* __restrict__ b1, const float* __restrict__ W2,
    const float* __restrict__ inv, float* __restrict__ cz, int N) {
  __shared__ float At[NFEAT * ATS];   // 18432 B
  __shared__ float Wt[16 * NHID];     // 16384 B  (one 16-row K-chunk of W1)
  int t = threadIdx.x;
  int m0 = blockIdx.x * BM;

  {
    int r = t >> 3;
    int kq = (t & 7) * 4;
    const float4* a4 = (const float4*)(agg + (size_t)(m0 + r) * NFEAT);
    bool ok = (m0 + r) < N;
#pragma unroll
    for (int p = 0; p < 4; ++p) {
      int k0 = kq + p * 32;
      float4 v = ok ? a4[k0 >> 2] : make_float4(0.f, 0.f, 0.f, 0.f);
      At[(k0 + 0) * ATS + r] = v.x;
      At[(k0 + 1) * ATS + r] = v.y;
      At[(k0 + 2) * ATS + r] = v.z;
      At[(k0 + 3) * ATS + r] = v.w;
    }
  }

  int rg = t >> 6, cg = t & 63;
  int r0 = rg * 8, rq = r0 >> 2;

  float4 acc[8];
#pragma unroll
  for (int i = 0; i < 8; ++i) acc[i] = make_float4(0.f, 0.f, 0.f, 0.f);

  const float4* At4 = (const float4*)At;
  const float4* Wt4 = (const float4*)Wt;
  const float4* W14 = (const float4*)W1;

  float4 r[4];
#pragma unroll
  for (int i = 0; i < 4; ++i) r[i] = W14[t + i * 256];   // chunk 0

  for (int kc = 0; kc < 8; ++kc) {
    __syncthreads();   // prev chunk consumed (kc=0: pairs with At-load)
#pragma unroll
    for (int i = 0; i < 4; ++i) ((float4*)Wt)[t + i * 256] = r[i];
    __syncthreads();   // Wt ready
    if (kc < 7) {
#pragma unroll
      for (int i = 0; i < 4; ++i) r[i] = W14[(kc + 1) * 1024 + t + i * 256];
    }
#pragma unroll 4
    for (int kk = 0; kk < 16; ++kk) {
      int k = kc * 16 + kk;
      float4 w  = Wt4[kk * 64 + cg];          // stride-1 across lanes
      float4 a0 = At4[9 * k + rq];            // broadcast
      float4 a1 = At4[9 * k + rq + 1];
      float av[8] = {a0.x, a0.y, a0.z, a0.w, a1.x, a1.y, a1.z, a1.w};
#pragma unroll
      for (int rr = 0; rr < 8; ++rr) {
        acc[rr].x = fmaf(av[rr], w.x, acc[rr].x);
        acc[rr].y = fmaf(av[rr], w.y, acc[rr].y);
        acc[rr].z = fmaf(av[rr], w.z, acc[rr].z);
        acc[rr].w = fmaf(av[rr], w.w, acc[rr].w);
      }
    }
  }

  int c0 = cg * 4;
  float4 bb = *(const float4*)(b1 + c0);
  float4 w2 = *(const float4*)(W2 + c0);
#pragma unroll
  for (int rr = 0; rr < 8; ++rr) {
    float hx = fmaxf(acc[rr].x + bb.x, 0.f);
    float hy = fmaxf(acc[rr].y + bb.y, 0.f);
    float hz = fmaxf(acc[rr].z + bb.z, 0.f);
    float hw = fmaxf(acc[rr].w + bb.w, 0.f);
    float pp = hx * w2.x + hy * w2.y + hz * w2.z + hw * w2.w;
#pragma unroll
    for (int off = 32; off > 0; off >>= 1) pp += __shfl_xor(pp, off);
    if (cg == 0) {
      int row = m0 + r0 + rr;
      if (row < N) cz[row] = inv[row] * pp;
    }
  }
}

// ---------------- layer-2 aggregation: thread per node ----------------
__global__ void k_agg2(const int* __restrict__ col, const int* __restrict__ row_ptr,
                       const float* __restrict__ inv, const float* __restrict__ cz,
                       const float* __restrict__ b2, float* __restrict__ out, int N) {
  int i = blockIdx.x * blockDim.x + threadIdx.x;
  if (i >= N) return;
  int beg = row_ptr[i], end = row_ptr[i + 1];
  float acc = cz[i];                           // self loop
  for (int p = beg; p < end; ++p) acc += cz[col[p]];
  out[i] = inv[i] * acc + b2[0];
}

extern "C" void kernel_launch(void* const* d_in, const int* in_sizes, int n_in,
                              void* d_out, int out_size, void* d_ws, size_t ws_size,
                              hipStream_t stream) {
  const float* x  = (const float*)d_in[0];
  const int*   ei = (const int*)d_in[1];
  const float* W1 = (const float*)d_in[2];
  const float* b1 = (const float*)d_in[3];
  const float* W2 = (const float*)d_in[4];
  const float* b2 = (const float*)d_in[5];
  int N = in_sizes[0] / NFEAT;
  int E = in_sizes[1] / 2;
  const int* src = ei;
  const int* dst = ei + E;
  float* out = (float*)d_out;

  char* w = (char*)d_ws;
  size_t o = 0;
  auto carve = [&](size_t bytes) { char* p = w + o; o += (bytes + 255) & ~(size_t)255; return p; };
  int*   deg      = (int*)  carve((size_t)N * 4);
  int*   row_ptr  = (int*)  carve((size_t)(N + 1) * 4);
  int*   cursor   = (int*)  carve((size_t)N * 4);
  float* inv      = (float*)carve((size_t)N * 4);
  int*   partials = (int*)  carve(1024 * 4);
  int*   col      = (int*)  carve((size_t)E * 4);
  float* agg      = (float*)carve((size_t)N * NFEAT * 4);
  float* cz       = (float*)deg;               // overlay: deg dead after scan1

  hipMemsetAsync(deg, 0, (size_t)N * sizeof(int), stream);

  int nparts = (N + 1023) / 1024;
  k_hist<<<(E + 255) / 256, 256, 0, stream>>>(dst, E, deg);
  k_scan1<<<nparts, 1024, 0, stream>>>(deg, N, row_ptr, inv, partials);
  k_scan2<<<1, 64, 0, stream>>>(partials, nparts, row_ptr + N);
  k_scan3<<<(N + 255) / 256, 256, 0, stream>>>(row_ptr, partials, cursor, N);
  k_scatter<<<(E + 255) / 256, 256, 0, stream>>>(src, dst, cursor, col, E);

  long long tot = (long long)N * 64;
  k_agg1_csr<<<(int)((tot + 255) / 256), 256, 0, stream>>>(
      (const float2*)x, col, row_ptr, inv, (float2*)agg, N);

  k_gemm_fused<<<(N + BM - 1) / BM, 256, 0, stream>>>(agg, W1, b1, W2, inv, cz, N);

  k_agg2<<<(N + 255) / 256, 256, 0, stream>>>(col, row_ptr, inv, cz, b2, out, N);
}

// Round 4
// 291.390 us; speedup vs baseline: 5.6806x; 1.0656x over previous
//
#include <hip/hip_runtime.h>

#define NFEAT 128
#define NHID  256
#define BM    32
#define ARS   132   // A-tile row stride in floats (128 + 4 pad): b64 stores conflict-free,
                    // row base 132*4 B is 16B-aligned so b128 broadcast reads work

// ---------------- degree histogram (int atomics) ----------------
__global__ void k_hist(const int* __restrict__ dst, int E, int* __restrict__ deg) {
  int i = blockIdx.x * blockDim.x + threadIdx.x;
  if (i < E) atomicAdd(&deg[dst[i]], 1);
}

// ---------------- 3-phase parallel scan ----------------
__global__ __launch_bounds__(1024) void k_scan1(const int* __restrict__ deg, int N,
                                                int* __restrict__ row_ptr,
                                                float* __restrict__ inv,
                                                int* __restrict__ partials) {
  __shared__ int wsum[16];
  int tid = threadIdx.x, lane = tid & 63, wid = tid >> 6;
  int idx = blockIdx.x * 1024 + tid;
  int v = (idx < N) ? deg[idx] : 0;
  int s = v;
#pragma unroll
  for (int off = 1; off < 64; off <<= 1) {
    int t = __shfl_up(s, off);
    if (lane >= off) s += t;
  }
  if (lane == 63) wsum[wid] = s;
  __syncthreads();
  int wbase = 0, total = 0;
#pragma unroll
  for (int w = 0; w < 16; ++w) {
    int t = wsum[w];
    total += t;
    if (w < wid) wbase += t;
  }
  if (idx < N) {
    row_ptr[idx] = wbase + (s - v);
    inv[idx] = rsqrtf((float)(v + 1));
  }
  if (tid == 0) partials[blockIdx.x] = total;
}

__global__ __launch_bounds__(64) void k_scan2(int* __restrict__ partials, int nparts,
                                              int* __restrict__ row_ptr_N) {
  int lane = threadIdx.x;
  int running = 0;
  for (int base = 0; base < nparts; base += 64) {
    int idx = base + lane;
    int v = (idx < nparts) ? partials[idx] : 0;
    int s = v;
#pragma unroll
    for (int off = 1; off < 64; off <<= 1) {
      int t = __shfl_up(s, off);
      if (lane >= off) s += t;
    }
    if (idx < nparts) partials[idx] = running + (s - v);
    running += __shfl(s, 63);
  }
  if (lane == 0) *row_ptr_N = running;
}

__global__ void k_scan3(int* __restrict__ row_ptr, const int* __restrict__ partials,
                        int* __restrict__ cursor, int N) {
  int idx = blockIdx.x * blockDim.x + threadIdx.x;
  if (idx < N) {
    int v = row_ptr[idx] + partials[idx >> 10];
    row_ptr[idx] = v;
    cursor[idx] = v;
  }
}

// ---------------- scatter edges into CSR order ----------------
__global__ void k_scatter(const int* __restrict__ src, const int* __restrict__ dst,
                          int* __restrict__ cursor, int* __restrict__ col, int E) {
  int e = blockIdx.x * blockDim.x + threadIdx.x;
  if (e < E) {
    int pos = atomicAdd(&cursor[dst[e]], 1);
    col[pos] = src[e];
  }
}

// ---------------- FUSED: CSR gather-aggregate -> LDS tile -> GEMM -> cz ----------------
// Block = 256 threads, 32 rows. Phase 1: wave w aggregates rows w*8..w*8+7 of
// A = D^-1/2(A+I)D^-1/2 X into LDS (row-major, stride ARS). Phase 2: register-
// resident W1 GEMM (no LDS for W, no barriers in K-loop), fused relu+W2 epilogue.
__global__ __launch_bounds__(256, 3) void k_agg_gemm(
    const float2* __restrict__ x2, const int* __restrict__ col,
    const int* __restrict__ row_ptr, const float* __restrict__ inv,
    const float* __restrict__ W1, const float* __restrict__ b1,
    const float* __restrict__ W2, float* __restrict__ cz, int N) {
  __shared__ float As[BM * ARS];          // 16896 B
  int t = threadIdx.x, wave = t >> 6, lane = t & 63;
  int m0 = blockIdx.x * BM;
  int r0 = wave * 8;

  // ---- phase 1: gather-aggregate 8 rows per wave ----
  for (int rr = 0; rr < 8; ++rr) {
    int r = r0 + rr;
    int node = m0 + r;
    float2 acc = make_float2(0.f, 0.f);
    if (node < N) {
      int beg = row_ptr[node], end = row_ptr[node + 1];
      float invd = inv[node];
      float2 xd = x2[(size_t)node * 64 + lane];
      float cs = invd * invd;
      acc.x = xd.x * cs; acc.y = xd.y * cs;
      int p = beg;
      for (; p + 3 < end; p += 4) {
        int s0 = col[p], s1 = col[p + 1], s2 = col[p + 2], s3 = col[p + 3];
        float c0 = inv[s0] * invd, c1 = inv[s1] * invd;
        float c2 = inv[s2] * invd, c3 = inv[s3] * invd;
        float2 v0 = x2[(size_t)s0 * 64 + lane];
        float2 v1 = x2[(size_t)s1 * 64 + lane];
        float2 v2 = x2[(size_t)s2 * 64 + lane];
        float2 v3 = x2[(size_t)s3 * 64 + lane];
        acc.x = fmaf(v0.x, c0, acc.x); acc.y = fmaf(v0.y, c0, acc.y);
        acc.x = fmaf(v1.x, c1, acc.x); acc.y = fmaf(v1.y, c1, acc.y);
        acc.x = fmaf(v2.x, c2, acc.x); acc.y = fmaf(v2.y, c2, acc.y);
        acc.x = fmaf(v3.x, c3, acc.x); acc.y = fmaf(v3.y, c3, acc.y);
      }
      for (; p < end; ++p) {
        int s0 = col[p];
        float c0 = inv[s0] * invd;
        float2 v0 = x2[(size_t)s0 * 64 + lane];
        acc.x = fmaf(v0.x, c0, acc.x); acc.y = fmaf(v0.y, c0, acc.y);
      }
    }
    *(float2*)&As[r * ARS + 2 * lane] = acc;   // b64, banks 2l..2l+1: conflict-free
  }
  __syncthreads();                              // the ONLY barrier

  // ---- phase 2: GEMM, W1 in registers via coalesced L2-hit loads ----
  const float4* As4 = (const float4*)As;        // row stride ARS/4 = 33
  const float4* W14 = (const float4*)W1;        // [k][64 float4 cols]

  float4 acc[8];
#pragma unroll
  for (int i = 0; i < 8; ++i) acc[i] = make_float4(0.f, 0.f, 0.f, 0.f);

  float4 wc[4], wn[4];
#pragma unroll
  for (int j = 0; j < 4; ++j) wc[j] = W14[j * 64 + lane];   // chunk 0

  for (int kc = 0; kc < 32; ++kc) {             // 32 chunks of 4 k
    if (kc < 31) {
#pragma unroll
      for (int j = 0; j < 4; ++j) wn[j] = W14[((kc + 1) * 4 + j) * 64 + lane];
    }
    float4 a[8];
#pragma unroll
    for (int rr = 0; rr < 8; ++rr)
      a[rr] = As4[(r0 + rr) * 33 + kc];         // broadcast b128: A[r][4kc..4kc+3]
#pragma unroll
    for (int j = 0; j < 4; ++j) {
      float4 w = wc[j];
#pragma unroll
      for (int rr = 0; rr < 8; ++rr) {
        float av = (j == 0) ? a[rr].x : (j == 1) ? a[rr].y : (j == 2) ? a[rr].z : a[rr].w;
        acc[rr].x = fmaf(av, w.x, acc[rr].x);
        acc[rr].y = fmaf(av, w.y, acc[rr].y);
        acc[rr].z = fmaf(av, w.z, acc[rr].z);
        acc[rr].w = fmaf(av, w.w, acc[rr].w);
      }
    }
#pragma unroll
    for (int j = 0; j < 4; ++j) wc[j] = wn[j];
  }

  // ---- epilogue: +b1, relu, dot W2, wave-reduce, scale by inv ----
  int c0 = lane * 4;
  float4 bb = *(const float4*)(b1 + c0);
  float4 w2 = *(const float4*)(W2 + c0);
#pragma unroll
  for (int rr = 0; rr < 8; ++rr) {
    float hx = fmaxf(acc[rr].x + bb.x, 0.f);
    float hy = fmaxf(acc[rr].y + bb.y, 0.f);
    float hz = fmaxf(acc[rr].z + bb.z, 0.f);
    float hw = fmaxf(acc[rr].w + bb.w, 0.f);
    float pp = hx * w2.x + hy * w2.y + hz * w2.z + hw * w2.w;
#pragma unroll
    for (int off = 32; off > 0; off >>= 1) pp += __shfl_xor(pp, off);
    if (lane == 0) {
      int row = m0 + r0 + rr;
      if (row < N) cz[row] = inv[row] * pp;
    }
  }
}

// ---------------- layer-2 aggregation: 4 lanes per node ----------------
__global__ void k_agg2(const int* __restrict__ col, const int* __restrict__ row_ptr,
                       const float* __restrict__ inv, const float* __restrict__ cz,
                       const float* __restrict__ b2, float* __restrict__ out, int N) {
  int g = blockIdx.x * blockDim.x + threadIdx.x;
  int node = g >> 2, q = g & 3;
  if (node >= N) return;
  int beg = row_ptr[node], end = row_ptr[node + 1];
  float acc = (q == 0) ? cz[node] : 0.f;        // self loop
  for (int p = beg + q; p < end; p += 4) acc += cz[col[p]];
  acc += __shfl_xor(acc, 1);
  acc += __shfl_xor(acc, 2);
  if (q == 0) out[node] = inv[node] * acc + b2[0];
}

extern "C" void kernel_launch(void* const* d_in, const int* in_sizes, int n_in,
                              void* d_out, int out_size, void* d_ws, size_t ws_size,
                              hipStream_t stream) {
  const float* x  = (const float*)d_in[0];
  const int*   ei = (const int*)d_in[1];
  const float* W1 = (const float*)d_in[2];
  const float* b1 = (const float*)d_in[3];
  const float* W2 = (const float*)d_in[4];
  const float* b2 = (const float*)d_in[5];
  int N = in_sizes[0] / NFEAT;
  int E = in_sizes[1] / 2;
  const int* src = ei;
  const int* dst = ei + E;
  float* out = (float*)d_out;

  char* w = (char*)d_ws;
  size_t o = 0;
  auto carve = [&](size_t bytes) { char* p = w + o; o += (bytes + 255) & ~(size_t)255; return p; };
  int*   deg      = (int*)  carve((size_t)N * 4);
  int*   row_ptr  = (int*)  carve((size_t)(N + 1) * 4);
  int*   cursor   = (int*)  carve((size_t)N * 4);
  float* inv      = (float*)carve((size_t)N * 4);
  int*   partials = (int*)  carve(1024 * 4);
  int*   col      = (int*)  carve((size_t)E * 4);
  float* cz       = (float*)deg;               // overlay: deg dead after scan1

  hipMemsetAsync(deg, 0, (size_t)N * sizeof(int), stream);

  int nparts = (N + 1023) / 1024;
  k_hist<<<(E + 255) / 256, 256, 0, stream>>>(dst, E, deg);
  k_scan1<<<nparts, 1024, 0, stream>>>(deg, N, row_ptr, inv, partials);
  k_scan2<<<1, 64, 0, stream>>>(partials, nparts, row_ptr + N);
  k_scan3<<<(N + 255) / 256, 256, 0, stream>>>(row_ptr, partials, cursor, N);
  k_scatter<<<(E + 255) / 256, 256, 0, stream>>>(src, dst, cursor, col, E);

  k_agg_gemm<<<(N + BM - 1) / BM, 256, 0, stream>>>(
      (const float2*)x, col, row_ptr, inv, W1, b1, W2, cz, N);

  long long tot2 = (long long)N * 4;
  k_agg2<<<(int)((tot2 + 255) / 256), 256, 0, stream>>>(col, row_ptr, inv, cz, b2, out, N);
}